// Round 8
// baseline (51.853 us; speedup 1.0000x reference)
//
#include <hip/hip_runtime.h>
#include <math.h>

#define T_LEN 2048
#define LN_EPS 1e-5f
#define M_ROWS 8192

using u16x8  = __attribute__((ext_vector_type(8))) unsigned short;
using bf16x8 = __attribute__((ext_vector_type(8))) short;
using f32x4  = __attribute__((ext_vector_type(4))) float;

__device__ __forceinline__ unsigned short f2bf(float f) {
    unsigned int u = __float_as_uint(f);
    u += 0x7FFFu + ((u >> 16) & 1u);
    return (unsigned short)(u >> 16);
}
__device__ __forceinline__ float bf2f(unsigned short u) {
    return __uint_as_float(((unsigned int)u) << 16);
}

// ---------------------------------------------------------------------------
// fp32 -> bf16 weights only: {w_qkv, w_out, w1, w2} = 524288 elems.
// ---------------------------------------------------------------------------
__global__ __launch_bounds__(256) void conv_w(
    const float* __restrict__ s1, const float* __restrict__ s2,
    const float* __restrict__ s3, const float* __restrict__ s4,
    unsigned short* __restrict__ dst)
{
    const int i8 = (blockIdx.x * 256 + threadIdx.x) * 8;
    const float* src; int off;
    if (i8 < 196608)      { src = s1; off = 0; }
    else if (i8 < 262144) { src = s2; off = 196608; }
    else if (i8 < 393216) { src = s3; off = 262144; }
    else                  { src = s4; off = 393216; }
    const float4 a = *(const float4*)(src + (i8 - off));
    const float4 c = *(const float4*)(src + (i8 - off) + 4);
    u16x8 p;
    p[0] = f2bf(a.x); p[1] = f2bf(a.y); p[2] = f2bf(a.z); p[3] = f2bf(a.w);
    p[4] = f2bf(c.x); p[5] = f2bf(c.y); p[6] = f2bf(c.z); p[7] = f2bf(c.w);
    *(u16x8*)(dst + i8) = p;
}

// ---------------------------------------------------------------------------
// mega_v2: one block = 32 output rows; weights read global->VGPR per-fragment
// (no LDS weight staging, no per-K-step barriers). LDS only for A-operands:
//  smF[48][256] bf16 (features halo), smQ[48][776] (qkv; later smH[32][512]),
//  smA[32][256] (attn-out / x), part[8][32][2].
// ---------------------------------------------------------------------------
__global__ __launch_bounds__(512) void mega_v2(
    const float* __restrict__ features,
    const unsigned short* __restrict__ Wqkv, const float* __restrict__ b_qkv,
    const unsigned short* __restrict__ Wo, const float* __restrict__ b_out,
    const unsigned short* __restrict__ W1, const float* __restrict__ b1,
    const unsigned short* __restrict__ W2, const float* __restrict__ b2,
    const float* __restrict__ g1, const float* __restrict__ be1,
    const float* __restrict__ g2, const float* __restrict__ be2,
    float* __restrict__ out)
{
    __shared__ __align__(16) char sm[117504];
    char* smF = sm;                       // [48][512 B]  = 24576
    char* smQ = sm + 24576;               // [48][1552 B] = 74496
    char* smA = sm + 99072;               // [32][512 B]  = 16384
    char* smH = smQ;                      // alias: [32][1024 B] = 32768
    float* part = (float*)(sm + 115456);  // [8][32][2]

    const int tid = threadIdx.x, lane = tid & 63, wid = tid >> 6;
    const int m0 = blockIdx.x * 32;
    const int b = m0 >> 11, t0 = m0 & 2047;

    // ================= P0: features halo -> smF bf16 (swizzled) =================
    #pragma unroll
    for (int j = 0; j < 3; ++j) {
        const int i = j * 512 + tid;          // 1536 chunks of 16 B
        const int e = i >> 5, ch = i & 31;
        const int gt = min(max(t0 - 4 + e, 0), T_LEN - 1);
        const float* src = features + ((size_t)(b * T_LEN + gt)) * 256 + ch * 8;
        const float4 a = *(const float4*)src;
        const float4 c = *(const float4*)(src + 4);
        u16x8 p;
        p[0] = f2bf(a.x); p[1] = f2bf(a.y); p[2] = f2bf(a.z); p[3] = f2bf(a.w);
        p[4] = f2bf(c.x); p[5] = f2bf(c.y); p[6] = f2bf(c.z); p[7] = f2bf(c.w);
        *(u16x8*)(smF + e * 512 + ((ch ^ (e & 7)) << 4)) = p;
    }
    __syncthreads();

    // ================= P1: qkv GEMM 48x768 (reg-weights) -> smQ =================
    for (int nc = 0; nc < 3; ++nc) {
        f32x4 acc[3][2];
        #pragma unroll
        for (int m = 0; m < 3; ++m)
            #pragma unroll
            for (int n = 0; n < 2; ++n) acc[m][n] = (f32x4)(0.f);

        #pragma unroll
        for (int kg = 0; kg < 2; ++kg) {
            bf16x8 bfr[2][4], af[3][4];
            #pragma unroll
            for (int n = 0; n < 2; ++n)
                #pragma unroll
                for (int ks = 0; ks < 4; ++ks) {
                    const int row = nc * 256 + wid * 32 + n * 16 + (lane & 15);
                    bfr[n][ks] = *(const bf16x8*)(Wqkv + (size_t)row * 256
                                 + (kg * 4 + ks) * 32 + (lane >> 4) * 8);
                }
            #pragma unroll
            for (int m = 0; m < 3; ++m)
                #pragma unroll
                for (int ks = 0; ks < 4; ++ks) {
                    const int r = m * 16 + (lane & 15);
                    const int ch = (kg * 4 + ks) * 4 + (lane >> 4);
                    af[m][ks] = *(const bf16x8*)(smF + r * 512 + ((ch ^ (r & 7)) << 4));
                }
            #pragma unroll
            for (int ks = 0; ks < 4; ++ks)
                #pragma unroll
                for (int m = 0; m < 3; ++m)
                    #pragma unroll
                    for (int n = 0; n < 2; ++n)
                        acc[m][n] = __builtin_amdgcn_mfma_f32_16x16x32_bf16(
                            af[m][ks], bfr[n][ks], acc[m][n], 0, 0, 0);
        }
        // epilogue -> smQ[48][776]
        #pragma unroll
        for (int n = 0; n < 2; ++n) {
            const int cl = wid * 32 + n * 16 + (lane & 15);
            const float bv = b_qkv[nc * 256 + cl];
            #pragma unroll
            for (int m = 0; m < 3; ++m) {
                const int rb = m * 16 + ((lane >> 4) << 2);
                #pragma unroll
                for (int j = 0; j < 4; ++j)
                    *(unsigned short*)(smQ + ((size_t)(rb + j) * 776 + nc * 256 + cl) * 2) =
                        f2bf(acc[m][n][j] + bv);
            }
        }
    }
    __syncthreads();

    // ================= P2: windowed attention (LDS reads) -> smA =================
    if (tid < 256) {
        const int h = tid & 7, tl = tid >> 3;

        float q[32];
        #pragma unroll
        for (int jj = 0; jj < 4; ++jj) {
            u16x8 u = *(const u16x8*)(smQ + ((tl + 4) * 776 + h * 32 + jj * 8) * 2);
            #pragma unroll
            for (int e = 0; e < 8; ++e) q[jj * 8 + e] = bf2f(u[e]);
        }

        float sc[9], mx = -1e30f;
        #pragma unroll
        for (int j = 0; j < 9; ++j) {
            const int kr0 = t0 + tl - 4 + j;
            const bool valid = (kr0 >= 0) && (kr0 < T_LEN);
            const char* kr = smQ + ((tl + j) * 776 + 256 + h * 32) * 2;
            float d = 0.f;
            #pragma unroll
            for (int jj = 0; jj < 4; ++jj) {
                u16x8 u = *(const u16x8*)(kr + jj * 16);
                #pragma unroll
                for (int e = 0; e < 8; ++e) d += q[jj * 8 + e] * bf2f(u[e]);
            }
            sc[j] = valid ? d * 0.17677669529663687f : -1e30f;
            mx = fmaxf(mx, sc[j]);
        }
        float sum = 0.f;
        #pragma unroll
        for (int j = 0; j < 9; ++j) { sc[j] = expf(sc[j] - mx); sum += sc[j]; }
        const float inv = 1.f / sum;

        float ov[32] = {};
        #pragma unroll
        for (int j = 0; j < 9; ++j) {
            const float p = sc[j] * inv;
            const char* vr = smQ + ((tl + j) * 776 + 512 + h * 32) * 2;
            #pragma unroll
            for (int jj = 0; jj < 4; ++jj) {
                u16x8 u = *(const u16x8*)(vr + jj * 16);
                #pragma unroll
                for (int e = 0; e < 8; ++e) ov[jj * 8 + e] += p * bf2f(u[e]);
            }
        }
        #pragma unroll
        for (int jj = 0; jj < 4; ++jj) {
            u16x8 p8;
            #pragma unroll
            for (int e = 0; e < 8; ++e) p8[e] = f2bf(ov[jj * 8 + e]);
            const int off = tl * 512 + ((h * 4 + jj) ^ (tl & 7)) * 16;
            *(u16x8*)(smA + off) = p8;
        }
    }
    __syncthreads();

    // ======== P3: out-proj 32x256 (reg-weights) + res + LN1 -> x ========
    float xres[2][2][4];     // LN1 output at this thread's (r,c) positions
    {
        f32x4 acc[2][2];
        #pragma unroll
        for (int m = 0; m < 2; ++m)
            #pragma unroll
            for (int n = 0; n < 2; ++n) acc[m][n] = (f32x4)(0.f);

        #pragma unroll
        for (int kg = 0; kg < 2; ++kg) {
            bf16x8 bfr[2][4], af[2][4];
            #pragma unroll
            for (int n = 0; n < 2; ++n)
                #pragma unroll
                for (int ks = 0; ks < 4; ++ks) {
                    const int row = wid * 32 + n * 16 + (lane & 15);
                    bfr[n][ks] = *(const bf16x8*)(Wo + (size_t)row * 256
                                 + (kg * 4 + ks) * 32 + (lane >> 4) * 8);
                }
            #pragma unroll
            for (int m = 0; m < 2; ++m)
                #pragma unroll
                for (int ks = 0; ks < 4; ++ks) {
                    const int r = m * 16 + (lane & 15);
                    const int ch = (kg * 4 + ks) * 4 + (lane >> 4);
                    af[m][ks] = *(const bf16x8*)(smA + r * 512 + ((ch ^ (r & 7)) << 4));
                }
            #pragma unroll
            for (int ks = 0; ks < 4; ++ks)
                #pragma unroll
                for (int m = 0; m < 2; ++m)
                    #pragma unroll
                    for (int n = 0; n < 2; ++n)
                        acc[m][n] = __builtin_amdgcn_mfma_f32_16x16x32_bf16(
                            af[m][ks], bfr[n][ks], acc[m][n], 0, 0, 0);
        }

        // epilogue: + b_out + features, LN1 -> smA (bf16) + xres regs
        float v[2][2][4], s[2][4], sq[2][4];
        #pragma unroll
        for (int m = 0; m < 2; ++m)
            #pragma unroll
            for (int j = 0; j < 4; ++j) { s[m][j] = 0.f; sq[m][j] = 0.f; }
        #pragma unroll
        for (int n = 0; n < 2; ++n) {
            const int c = wid * 32 + n * 16 + (lane & 15);
            const float bv = b_out[c];
            #pragma unroll
            for (int m = 0; m < 2; ++m) {
                const int rb = m * 16 + ((lane >> 4) << 2);
                #pragma unroll
                for (int j = 0; j < 4; ++j) {
                    float x = acc[m][n][j] + bv + features[(size_t)(m0 + rb + j) * 256 + c];
                    v[m][n][j] = x; s[m][j] += x; sq[m][j] += x * x;
                }
            }
        }
        #pragma unroll
        for (int m = 0; m < 2; ++m)
            #pragma unroll
            for (int j = 0; j < 4; ++j) {
                #pragma unroll
                for (int msk = 1; msk <= 8; msk <<= 1) {
                    s[m][j]  += __shfl_xor(s[m][j], msk);
                    sq[m][j] += __shfl_xor(sq[m][j], msk);
                }
                if ((lane & 15) == 0) {
                    const int r = m * 16 + ((lane >> 4) << 2) + j;
                    part[(wid * 32 + r) * 2 + 0] = s[m][j];
                    part[(wid * 32 + r) * 2 + 1] = sq[m][j];
                }
            }
        __syncthreads();   // also fences all waves' smA reads above
        #pragma unroll
        for (int m = 0; m < 2; ++m) {
            const int rb = m * 16 + ((lane >> 4) << 2);
            #pragma unroll
            for (int j = 0; j < 4; ++j) {
                const int r = rb + j;
                float S = 0.f, SQ = 0.f;
                #pragma unroll
                for (int w = 0; w < 8; ++w) {
                    S += part[(w * 32 + r) * 2 + 0]; SQ += part[(w * 32 + r) * 2 + 1];
                }
                const float mean = S * (1.f / 256.f);
                const float var  = SQ * (1.f / 256.f) - mean * mean;
                const float rstd = rsqrtf(var + LN_EPS);
                #pragma unroll
                for (int n = 0; n < 2; ++n) {
                    const int c = wid * 32 + n * 16 + (lane & 15);
                    const float o = (v[m][n][j] - mean) * rstd * g1[c] + be1[c];
                    xres[m][n][j] = o;
                    const int addr = r * 512 + (((c >> 3) ^ (r & 7)) << 4) + ((c & 7) << 1);
                    *(unsigned short*)(smA + addr) = f2bf(o);
                }
            }
        }
    }
    __syncthreads();

    // ================= P4: FFN1 32x512 (reg-weights, relu) -> smH =================
    #pragma unroll
    for (int nh = 0; nh < 2; ++nh) {
        f32x4 acc[2][2];
        #pragma unroll
        for (int m = 0; m < 2; ++m)
            #pragma unroll
            for (int n = 0; n < 2; ++n) acc[m][n] = (f32x4)(0.f);

        #pragma unroll
        for (int kg = 0; kg < 2; ++kg) {
            bf16x8 bfr[2][4], af[2][4];
            #pragma unroll
            for (int n = 0; n < 2; ++n)
                #pragma unroll
                for (int ks = 0; ks < 4; ++ks) {
                    const int row = nh * 256 + wid * 32 + n * 16 + (lane & 15);
                    bfr[n][ks] = *(const bf16x8*)(W1 + (size_t)row * 256
                                 + (kg * 4 + ks) * 32 + (lane >> 4) * 8);
                }
            #pragma unroll
            for (int m = 0; m < 2; ++m)
                #pragma unroll
                for (int ks = 0; ks < 4; ++ks) {
                    const int r = m * 16 + (lane & 15);
                    const int ch = (kg * 4 + ks) * 4 + (lane >> 4);
                    af[m][ks] = *(const bf16x8*)(smA + r * 512 + ((ch ^ (r & 7)) << 4));
                }
            #pragma unroll
            for (int ks = 0; ks < 4; ++ks)
                #pragma unroll
                for (int m = 0; m < 2; ++m)
                    #pragma unroll
                    for (int n = 0; n < 2; ++n)
                        acc[m][n] = __builtin_amdgcn_mfma_f32_16x16x32_bf16(
                            af[m][ks], bfr[n][ks], acc[m][n], 0, 0, 0);
        }
        // relu(acc + b1) -> smH[32][512] (swizzled scalar writes)
        #pragma unroll
        for (int n = 0; n < 2; ++n) {
            const int c = nh * 256 + wid * 32 + n * 16 + (lane & 15);
            const float bv = b1[c];
            #pragma unroll
            for (int m = 0; m < 2; ++m) {
                const int rb = m * 16 + ((lane >> 4) << 2);
                #pragma unroll
                for (int j = 0; j < 4; ++j) {
                    const int r = rb + j;
                    const int addr = r * 1024 + (((c >> 3) ^ (r & 7)) << 4) + ((c & 7) << 1);
                    *(unsigned short*)(smH + addr) = f2bf(fmaxf(acc[m][n][j] + bv, 0.f));
                }
            }
        }
    }
    __syncthreads();

    // ========= P5: FFN2 32x256 K=512 (reg-weights) + xres + LN2 -> out =========
    {
        f32x4 acc[2][2];
        #pragma unroll
        for (int m = 0; m < 2; ++m)
            #pragma unroll
            for (int n = 0; n < 2; ++n) acc[m][n] = (f32x4)(0.f);

        #pragma unroll
        for (int kg = 0; kg < 4; ++kg) {
            bf16x8 bfr[2][4], af[2][4];
            #pragma unroll
            for (int n = 0; n < 2; ++n)
                #pragma unroll
                for (int ks = 0; ks < 4; ++ks) {
                    const int row = wid * 32 + n * 16 + (lane & 15);
                    bfr[n][ks] = *(const bf16x8*)(W2 + (size_t)row * 512
                                 + (kg * 4 + ks) * 32 + (lane >> 4) * 8);
                }
            #pragma unroll
            for (int m = 0; m < 2; ++m)
                #pragma unroll
                for (int ks = 0; ks < 4; ++ks) {
                    const int r = m * 16 + (lane & 15);
                    const int ch = (kg * 4 + ks) * 4 + (lane >> 4);   // 0..63
                    af[m][ks] = *(const bf16x8*)(smH + r * 1024 + ((ch ^ (r & 7)) << 4));
                }
            #pragma unroll
            for (int ks = 0; ks < 4; ++ks)
                #pragma unroll
                for (int m = 0; m < 2; ++m)
                    #pragma unroll
                    for (int n = 0; n < 2; ++n)
                        acc[m][n] = __builtin_amdgcn_mfma_f32_16x16x32_bf16(
                            af[m][ks], bfr[n][ks], acc[m][n], 0, 0, 0);
        }

        // epilogue: + b2 + xres, LN2 -> out (f32)
        float v[2][2][4], s[2][4], sq[2][4];
        #pragma unroll
        for (int m = 0; m < 2; ++m)
            #pragma unroll
            for (int j = 0; j < 4; ++j) { s[m][j] = 0.f; sq[m][j] = 0.f; }
        #pragma unroll
        for (int n = 0; n < 2; ++n) {
            #pragma unroll
            for (int m = 0; m < 2; ++m) {
                #pragma unroll
                for (int j = 0; j < 4; ++j) {
                    const int c = wid * 32 + n * 16 + (lane & 15);
                    float x = acc[m][n][j] + b2[c] + xres[m][n][j];
                    v[m][n][j] = x; s[m][j] += x; sq[m][j] += x * x;
                }
            }
        }
        #pragma unroll
        for (int m = 0; m < 2; ++m)
            #pragma unroll
            for (int j = 0; j < 4; ++j) {
                #pragma unroll
                for (int msk = 1; msk <= 8; msk <<= 1) {
                    s[m][j]  += __shfl_xor(s[m][j], msk);
                    sq[m][j] += __shfl_xor(sq[m][j], msk);
                }
                if ((lane & 15) == 0) {
                    const int r = m * 16 + ((lane >> 4) << 2) + j;
                    part[(wid * 32 + r) * 2 + 0] = s[m][j];
                    part[(wid * 32 + r) * 2 + 1] = sq[m][j];
                }
            }
        __syncthreads();
        #pragma unroll
        for (int m = 0; m < 2; ++m) {
            const int rb = m * 16 + ((lane >> 4) << 2);
            #pragma unroll
            for (int j = 0; j < 4; ++j) {
                const int r = rb + j;
                float S = 0.f, SQ = 0.f;
                #pragma unroll
                for (int w = 0; w < 8; ++w) {
                    S += part[(w * 32 + r) * 2 + 0]; SQ += part[(w * 32 + r) * 2 + 1];
                }
                const float mean = S * (1.f / 256.f);
                const float var  = SQ * (1.f / 256.f) - mean * mean;
                const float rstd = rsqrtf(var + LN_EPS);
                #pragma unroll
                for (int n = 0; n < 2; ++n) {
                    const int c = wid * 32 + n * 16 + (lane & 15);
                    const float o = (v[m][n][j] - mean) * rstd * g2[c] + be2[c];
                    out[(size_t)(m0 + r) * 256 + c] = o;
                }
            }
        }
    }
}

// ---------------------------------------------------------------------------
extern "C" void kernel_launch(void* const* d_in, const int* in_sizes, int n_in,
                              void* d_out, int out_size, void* d_ws, size_t ws_size,
                              hipStream_t stream) {
    const float* features = (const float*)d_in[0];
    const float* w_qkv    = (const float*)d_in[1];
    const float* b_qkv    = (const float*)d_in[2];
    const float* w_out    = (const float*)d_in[3];
    const float* b_out    = (const float*)d_in[4];
    const float* w1       = (const float*)d_in[5];
    const float* b1       = (const float*)d_in[6];
    const float* w2       = (const float*)d_in[7];
    const float* b2       = (const float*)d_in[8];
    const float* g1       = (const float*)d_in[9];
    const float* be1      = (const float*)d_in[10];
    const float* g2       = (const float*)d_in[11];
    const float* be2      = (const float*)d_in[12];
    // d_in[13] (mask) structurally determined by WIN=9 -> not read.

    unsigned short* wsu = (unsigned short*)d_ws;
    unsigned short* wqkvbf = wsu;               // 196,608
    unsigned short* woutbf = wsu + 196608;      //  65,536
    unsigned short* w1bf   = wsu + 262144;      // 131,072
    unsigned short* w2bf   = wsu + 393216;      // 131,072

    // 1) convert weights to bf16 (1 MB total)
    conv_w<<<256, 256, 0, stream>>>(w_qkv, w_out, w1, w2, wsu);
    // 2) fully fused encoder (register-resident weight fragments)
    mega_v2<<<M_ROWS / 32, 512, 0, stream>>>(
        features, wqkvbf, b_qkv, woutbf, b_out, w1bf, b1, w2bf, b2,
        g1, be1, g2, be2, (float*)d_out);
}